// Round 17
// baseline (991.126 us; speedup 1.0000x reference)
//
#include <hip/hip_runtime.h>
#include <hip/hip_bf16.h>
#include <math.h>

#define VOCAB 50257
#define VPAD  50432          // VOCAB padded to multiple of 256
#define EMB   1024
#define NROWS 4096

#define BM 256
#define BN 256
#define BK 64
#define NKT (EMB / BK)       // 16
#define NMT (NROWS / BM)     // 16
#define NT  (VPAD / BN)      // 197
#define NWG (NMT * NT)       // 3152 (divisible by 8)

typedef __attribute__((ext_vector_type(4))) float  f32x4;
typedef __attribute__((ext_vector_type(16))) float f32x16;
typedef __attribute__((ext_vector_type(4), aligned(4))) float f32x4u;
typedef __attribute__((ext_vector_type(4))) __bf16 bf16x4;
typedef __attribute__((ext_vector_type(8))) __bf16 bf16x8;

#define FENCE asm volatile("" ::: "memory")
#define BARRIER do { FENCE; __builtin_amdgcn_s_barrier(); FENCE; } while (0)

// ---------------------------------------------------------------------------
// fp32 -> bf16 convert (pads tail with zeros). n_src, n_dst multiples of 8.
// ---------------------------------------------------------------------------
__global__ __launch_bounds__(256)
void cvt_bf16(const float* __restrict__ src, __bf16* __restrict__ dst,
              long n_src, long n_dst) {
    long i = ((long)blockIdx.x * 256 + threadIdx.x) * 8;
    if (i >= n_dst) return;
    bf16x8 o;
    if (i < n_src) {
        f32x4 a = *(const f32x4*)(src + i);
        f32x4 b = *(const f32x4*)(src + i + 4);
        #pragma unroll
        for (int e = 0; e < 4; ++e) {
            o[e]     = (__bf16)a[e];
            o[4 + e] = (__bf16)b[e];
        }
    } else {
        #pragma unroll
        for (int e = 0; e < 8; ++e) o[e] = (__bf16)0.0f;
    }
    *(bf16x8*)(dst + i) = o;
}

// ---------------------------------------------------------------------------
// 256x256-tile bf16 GEMM, 32x32x16 MFMA with FRAGMENT-MAJOR LDS:
//   tile stored as 1KB units [ks(0..3)][rblk(0..7)][lane(0..63) x 16B];
//   unit(ks,rblk) lane l = A[rblk*32 + (l&31)][kt*64 + ks*16 + (l>>5)*8 ..+8].
//   Every ds_read_b128 is base + lane*16  -> linear, ZERO bank conflicts.
//   global_load_lds dest stays linear; the permutation lives in the per-lane
//   GLOBAL source address (rule 21).
// R15 skeleton otherwise: 4-phase interleave, 2 LDS buffers, stage calendar
// (4 loads ph0 / 2 ph1 / 2 ph2, vmcnt(4)), 8mt x 2nt chunk map, unroll x2.
// Fused sum-exp epilogue (stores first). C/D: col=lane&31,
// row=(reg&3)+8*(reg>>2)+4*(lane>>5)  [m74/m101-verified].
// ---------------------------------------------------------------------------
template <bool LB_OUT>
__global__ __launch_bounds__(512, 2)
void gemm_fused(const __bf16* __restrict__ A, const __bf16* __restrict__ B,
                float* __restrict__ C, __bf16* __restrict__ Lb,
                float* __restrict__ pbuf) {
    __shared__ alignas(16) __bf16 S[65536];   // 128 KiB

    const int tid  = threadIdx.x;
    const int lane = tid & 63;
    const int wave = tid >> 6;
    const int wm   = (wave >> 2) * 128;       // 2 M-halves
    const int wn   = (wave & 3) * 64;         // 4 N-quarters
    const int l31  = lane & 31;
    const int h    = lane >> 5;

    // bijective XCD swizzle, then 8mt x 2nt chunks (<=6MB XCD-L2 hot window)
    const int b  = blockIdx.x;
    const int lg = (b & 7) * (NWG / 8) + (b >> 3);
    const int q  = lg >> 4, w = lg & 15;
    int mt, nt;
    if (q == 196) { mt = w; nt = 196; }
    else { mt = (q & 1) * 8 + (w & 7); nt = (q >> 1) * 2 + (w >> 3); }
    const int mtB = mt * BM, ntB = nt * BN;

    // staging source: lane reads 16B = row (wave*32 + l31), k-half h of a
    // 16-wide k-slice; one call covers units [u*8 .. u*8+8) = 8KB
    const __bf16* gA = A + (size_t)(mtB + wave * 32 + l31) * EMB + h * 8;
    const __bf16* gB = B + (size_t)(ntB + wave * 32 + l31) * EMB + h * 8;

    f32x16 acc[4][2];
    #pragma unroll
    for (int mb = 0; mb < 4; ++mb)
        #pragma unroll
        for (int nb = 0; nb < 2; ++nb)
            #pragma unroll
            for (int e = 0; e < 16; ++e) acc[mb][nb][e] = 0.0f;

#define GLOAD(gp, dp)                                                         \
    __builtin_amdgcn_global_load_lds(                                         \
        (const __attribute__((address_space(1))) void*)(gp),                 \
        (__attribute__((address_space(3))) void*)(dp), 16, 0, 0)

    // stage call u (0..3): unit (ks=u, rblk=wave) of A or B for K-tile kt
#define STAGE_A(bc, kt, u)                                                    \
    GLOAD(gA + (size_t)(kt) * BK + (u) * 16,                                  \
          &S[(bc) * 32768 + ((u) * 8 + wave) * 512])

#define STAGE_B(bc, kt, u)                                                    \
    GLOAD(gB + (size_t)(kt) * BK + (u) * 16,                                  \
          &S[(bc) * 32768 + 16384 + ((u) * 8 + wave) * 512])

    // fragment reads: linear base + lane*16
#define LDA32(dst, c, ks) { _Pragma("unroll")                                 \
    for (int mb_ = 0; mb_ < 4; ++mb_)                                         \
        dst[mb_] = *(const bf16x8*)&S[(c) * 32768                            \
            + (((ks) * 8) + ((wm >> 5) + mb_)) * 512 + lane * 8]; }

#define LDB32(dst, c, ks) { _Pragma("unroll")                                 \
    for (int nb_ = 0; nb_ < 2; ++nb_)                                         \
        dst[nb_] = *(const bf16x8*)&S[(c) * 32768 + 16384                    \
            + (((ks) * 8) + ((wn >> 5) + nb_)) * 512 + lane * 8]; }

#define MFMA8(AF, BF)                                                         \
    __builtin_amdgcn_s_setprio(1);                                            \
    _Pragma("unroll") for (int mb_ = 0; mb_ < 4; ++mb_)                       \
        _Pragma("unroll") for (int nb_ = 0; nb_ < 2; ++nb_)                   \
            acc[mb_][nb_] = __builtin_amdgcn_mfma_f32_32x32x16_bf16(          \
                AF[mb_], BF[nb_], acc[mb_][nb_], 0, 0, 0);                    \
    __builtin_amdgcn_s_setprio(0);

    bf16x8 afA[4], afB[4], bfrA[2], bfrB[2];

    // prologue: stage tile 0 into buf 0 (8 loads)
    #pragma unroll
    for (int u = 0; u < 4; ++u) { STAGE_A(0, 0, u); STAGE_B(0, 0, u); }

    #pragma unroll 2
    for (int t = 0; t < NKT; ++t) {
        const int c = t & 1;
        const bool pf = (t + 1 < NKT);
        // ---- phase 0 (ks0): stage 4 loads of t+1, wait tile t ----
        if (pf) {
            STAGE_A(c ^ 1, t + 1, 0); STAGE_B(c ^ 1, t + 1, 0);
            STAGE_A(c ^ 1, t + 1, 1); STAGE_B(c ^ 1, t + 1, 1);
            asm volatile("s_waitcnt vmcnt(4)" ::: "memory");  // tile t landed
        } else {
            asm volatile("s_waitcnt vmcnt(0)" ::: "memory");
        }
        BARRIER;
        LDB32(bfrA, c, 0); LDA32(afA, c, 0);
        LDB32(bfrB, c, 1); LDA32(afB, c, 1);   // ks1 fragments in flight
        MFMA8(afA, bfrA);
        // ---- phase 1 (ks1) ----
        if (pf) { STAGE_A(c ^ 1, t + 1, 2); STAGE_B(c ^ 1, t + 1, 2); }
        LDB32(bfrA, c, 2); LDA32(afA, c, 2);   // ks2 fragments in flight
        MFMA8(afB, bfrB);
        // ---- phase 2 (ks2) ----
        if (pf) { STAGE_A(c ^ 1, t + 1, 3); STAGE_B(c ^ 1, t + 1, 3); }
        LDB32(bfrB, c, 3); LDA32(afB, c, 3);   // ks3 fragments in flight
        MFMA8(afA, bfrA);
        // ---- phase 3 (ks3) ----
        MFMA8(afB, bfrB);
        BARRIER;                                // all waves done with buf c
    }
#undef STAGE_A
#undef STAGE_B
#undef GLOAD

    // ---------------- fused epilogue (stores first, sums under them) ------
    __syncthreads();                      // staging LDS reusable
    const bool edge = (ntB + BN > VOCAB); // only last nt tile

    if (LB_OUT) {
        #pragma unroll
        for (int mb = 0; mb < 4; ++mb) {
            #pragma unroll
            for (int r = 0; r < 16; ++r) {
                const int grow = mtB + wm + mb * 32 + (r & 3) + 8 * (r >> 2) + 4 * h;
                const size_t rb = (size_t)grow * VPAD + ntB + wn + l31;
                Lb[rb]      = (__bf16)acc[mb][0][r];
                Lb[rb + 32] = (__bf16)acc[mb][1][r];
            }
        }
    } else {
        #pragma unroll
        for (int mb = 0; mb < 4; ++mb) {
            #pragma unroll
            for (int r = 0; r < 16; ++r) {
                const int grow = mtB + wm + mb * 32 + (r & 3) + 8 * (r >> 2) + 4 * h;
                const size_t rb = (size_t)grow * VOCAB;
                const int col0 = ntB + wn + l31;
                if (!edge || col0 < VOCAB)      C[rb + col0]      = acc[mb][0][r];
                if (!edge || col0 + 32 < VOCAB) C[rb + col0 + 32] = acc[mb][1][r];
            }
        }
    }

    // per-lane exp-sums: fold cols via shfl_xor(16) -> LDS [256][68] f32
    float* ldsP = (float*)&S[0];
    const int col0 = ntB + wn + l31;
    #pragma unroll
    for (int mb = 0; mb < 4; ++mb) {
        #pragma unroll
        for (int r = 0; r < 16; ++r) {
            float s = 0.0f;
            if (!edge || col0 < VOCAB)      s += __expf(acc[mb][0][r]);
            if (!edge || col0 + 32 < VOCAB) s += __expf(acc[mb][1][r]);
            s += __shfl_xor(s, 16);
            if (l31 < 16) {
                const int lrow = wm + mb * 32 + (r & 3) + 8 * (r >> 2) + 4 * h;
                ldsP[lrow * 68 + (wave & 3) * 16 + (lane & 15)] = s;
            }
        }
    }
    __syncthreads();

    // reduce 64 partials per row -> pbuf[nt][global row]
    {
        const int rl = tid >> 1, hf = tid & 1;
        const float* q2 = ldsP + rl * 68 + hf * 32;
        float s = 0.0f;
        #pragma unroll
        for (int k = 0; k < 8; ++k) {
            f32x4 v = *(const f32x4*)(q2 + k * 4);
            s += v[0] + v[1] + v[2] + v[3];
        }
        s += __shfl_xor(s, 1);
        if (hf == 0) pbuf[(size_t)nt * NROWS + mtB + rl] = s;
    }
}

// ---------------------------------------------------------------------------
// reduce NT per-tile sumexp partials -> lse[row]; 64 rows per block
// ---------------------------------------------------------------------------
__global__ __launch_bounds__(256)
void lse_reduce(const float* __restrict__ pbuf, float* __restrict__ lse) {
    __shared__ float sl[4][64];
    const int r0 = blockIdx.x * 64;
    const int l  = threadIdx.x & 63;
    const int w  = threadIdx.x >> 6;
    float s = 0.0f;
    for (int t = w; t < NT; t += 4)
        s += pbuf[(size_t)t * NROWS + r0 + l];
    sl[w][l] = s;
    __syncthreads();
    if (threadIdx.x < 64)
        lse[r0 + l] = __logf(sl[0][l] + sl[1][l] + sl[2][l] + sl[3][l]);
}

// ---------------------------------------------------------------------------
// C[row][col] = (float)Lb[row][col] - lse[row]; 4 blocks per row (quarters),
// nontemporal load/store (read-once / write-once data).
// ---------------------------------------------------------------------------
__global__ __launch_bounds__(256)
void expand_sub(const __bf16* __restrict__ Lb, const float* __restrict__ lse,
                float* __restrict__ C) {
    const int row = blockIdx.x >> 2;
    const int q   = blockIdx.x & 3;
    const float s = lse[row];
    const __bf16* src = Lb + (size_t)row * VPAD;
    float* dst = C + (size_t)row * VOCAB;
    // 50257 = 8*6282 + 1; quarters of 1571 chunks (last quarter 1569 + tail)
    const int i0 = q * 1571;
    const int i1 = (q == 3) ? 6282 : i0 + 1571;
    for (int i = i0 + threadIdx.x; i < i1; i += 256) {
        bf16x8 v = __builtin_nontemporal_load((const bf16x8*)(src + i * 8));
        f32x4u a, b2;
        a[0] = (float)v[0] - s; a[1] = (float)v[1] - s;
        a[2] = (float)v[2] - s; a[3] = (float)v[3] - s;
        b2[0] = (float)v[4] - s; b2[1] = (float)v[5] - s;
        b2[2] = (float)v[6] - s; b2[3] = (float)v[7] - s;
        __builtin_nontemporal_store(a,  (f32x4u*)(dst + i * 8));
        __builtin_nontemporal_store(b2, (f32x4u*)(dst + i * 8 + 4));
    }
    if (q == 3 && threadIdx.x == 0)
        dst[50256] = (float)src[50256] - s;
}

// ---------------------------------------------------------------------------
// out[row][col] -= lse[row]; fallback when Lb doesn't fit
// ---------------------------------------------------------------------------
__global__ __launch_bounds__(256)
void sub_lse(float* __restrict__ C, const float* __restrict__ lse) {
    const int row = blockIdx.x;
    const float s = lse[row];
    float* p = C + (size_t)row * VOCAB;
    for (int i = threadIdx.x; i < 12564; i += 256) {
        f32x4u v = *(const f32x4u*)(p + 4 * i);
        v[0] -= s; v[1] -= s; v[2] -= s; v[3] -= s;
        *(f32x4u*)(p + 4 * i) = v;
    }
    if (threadIdx.x == 0) p[50256] -= s;
}

// ---------------------------------------------------------------------------
// fallback fp32-input GEMM (128x128, R1 structure) if ws too small
// ---------------------------------------------------------------------------
#define FBM 128
#define FBK 32
__device__ __forceinline__ int swz_idx(int row, int col) {
    int slot = (col >> 3) ^ ((row >> 1) & 3);
    return row * FBK + slot * 8 + (col & 7);
}

__global__ __launch_bounds__(256, 2)
void gemm_logits(const float* __restrict__ H, const float* __restrict__ W,
                 float* __restrict__ C) {
    __shared__ __bf16 ldsA[FBM * FBK];
    __shared__ __bf16 ldsB[FBM * FBK];

    const int tid  = threadIdx.x;
    const int lane = tid & 63;
    const int wave = tid >> 6;
    const int wm = (wave >> 1) * 64;
    const int wn = (wave & 1) * 64;
    const int mt = blockIdx.x;
    const int nt = blockIdx.y;
    const int srow = tid >> 1;
    const int scol = (tid & 1) * 16;
    const int brow_g = nt * FBM + srow;
    const bool bvalid = brow_g < VOCAB;
    const float* aptr = H + (size_t)(mt * FBM + srow) * EMB + scol;
    const float* bptr = W + (size_t)(bvalid ? brow_g : 0) * EMB + scol;

    f32x4 areg[4], breg[4];
    #pragma unroll
    for (int q = 0; q < 4; ++q) {
        areg[q] = *(const f32x4*)(aptr + q * 4);
        breg[q] = *(const f32x4*)(bptr + q * 4);
    }
    f32x4 acc[4][4];
    const f32x4 vzero = {0.f, 0.f, 0.f, 0.f};
    #pragma unroll
    for (int i = 0; i < 4; ++i)
        #pragma unroll
        for (int j = 0; j < 4; ++j) acc[i][j] = vzero;

    const int frow = lane & 15;
    const int kcol = (lane >> 4) * 8;

    for (int kt = 0; kt < EMB / FBK; ++kt) {
        __syncthreads();
        #pragma unroll
        for (int q = 0; q < 4; ++q) {
            const int col = scol + q * 4;
            bf16x4 av, bv;
            #pragma unroll
            for (int e = 0; e < 4; ++e) {
                av[e] = (__bf16)areg[q][e];
                bv[e] = bvalid ? (__bf16)breg[q][e] : (__bf16)0.0f;
            }
            *(bf16x4*)(&ldsA[swz_idx(srow, col)]) = av;
            *(bf16x4*)(&ldsB[swz_idx(srow, col)]) = bv;
        }
        __syncthreads();
        if (kt + 1 < EMB / FBK) {
            const int ko = (kt + 1) * FBK;
            #pragma unroll
            for (int q = 0; q < 4; ++q) {
                areg[q] = *(const f32x4*)(aptr + ko + q * 4);
                breg[q] = *(const f32x4*)(bptr + ko + q * 4);
            }
        }
        bf16x8 af[4], bfr[4];
        #pragma unroll
        for (int i = 0; i < 4; ++i) {
            af[i]  = *(const bf16x8*)(&ldsA[swz_idx(wm + i * 16 + frow, kcol)]);
            bfr[i] = *(const bf16x8*)(&ldsB[swz_idx(wn + i * 16 + frow, kcol)]);
        }
        #pragma unroll
        for (int i = 0; i < 4; ++i)
            #pragma unroll
            for (int j = 0; j < 4; ++j)
                acc[i][j] = __builtin_amdgcn_mfma_f32_16x16x32_bf16(
                    af[i], bfr[j], acc[i][j], 0, 0, 0);
    }

    const int crow = mt * FBM + wm + (lane >> 4) * 4;
    const int ccol = nt * FBM + wn + (lane & 15);
    #pragma unroll
    for (int i = 0; i < 4; ++i) {
        #pragma unroll
        for (int j = 0; j < 4; ++j) {
            const int col = ccol + j * 16;
            if (col < VOCAB) {
                #pragma unroll
                for (int r = 0; r < 4; ++r)
                    C[(size_t)(crow + i * 16 + r) * VOCAB + col] = acc[i][j][r];
            }
        }
    }
}

// ---------------------------------------------------------------------------
// fallback full row LSE
// ---------------------------------------------------------------------------
__global__ __launch_bounds__(256)
void row_lse(const float* __restrict__ C, float* __restrict__ lse) {
    const int row = blockIdx.x;
    const float* p = C + (size_t)row * VOCAB;

    float m = -INFINITY, l = 0.0f;
    for (int i = threadIdx.x; i < 12564; i += 256) {
        f32x4u v = *(const f32x4u*)(p + 4 * i);
        #pragma unroll
        for (int e = 0; e < 4; ++e) {
            const float x  = v[e];
            const float mn = fmaxf(m, x);
            l = l * __expf(m - mn) + __expf(x - mn);
            m = mn;
        }
    }
    if (threadIdx.x == 0) {
        const float x  = p[50256];
        const float mn = fmaxf(m, x);
        l = l * __expf(m - mn) + __expf(x - mn);
        m = mn;
    }
    #pragma unroll
    for (int off = 1; off < 64; off <<= 1) {
        const float mo = __shfl_xor(m, off);
        const float lo = __shfl_xor(l, off);
        const float mn = fmaxf(m, mo);
        l = l * __expf(m - mn) + lo * __expf(mo - mn);
        m = mn;
    }
    __shared__ float sm[4], sl[4];
    if ((threadIdx.x & 63) == 0) { sm[threadIdx.x >> 6] = m; sl[threadIdx.x >> 6] = l; }
    __syncthreads();
    if (threadIdx.x == 0) {
        m = sm[0]; l = sl[0];
        #pragma unroll
        for (int w = 1; w < 4; ++w) {
            const float mn = fmaxf(m, sm[w]);
            l = l * __expf(m - mn) + sl[w] * __expf(sm[w] - mn);
            m = mn;
        }
        lse[row] = m + __logf(l);
    }
}

// ---------------------------------------------------------------------------
extern "C" void kernel_launch(void* const* d_in, const int* in_sizes, int n_in,
                              void* d_out, int out_size, void* d_ws, size_t ws_size,
                              hipStream_t stream) {
    const float* H = (const float*)d_in[0];   // [4096][1024]
    const float* W = (const float*)d_in[1];   // [50257][1024]
    float* C   = (float*)d_out;               // [4096][50257]
    float* lse = (float*)d_ws;                // 4096 floats @ offset 0

    const long nH  = (long)NROWS * EMB;       // 4,194,304
    const long nW  = (long)VOCAB * EMB;       // 51,463,168
    const long nWp = (long)VPAD * EMB;        // 51,642,368

    // layout: lse | pbuf | Hb | Wb | Lb
    const size_t pb_off   = 16384;
    const size_t pb_bytes = (size_t)NT * NROWS * sizeof(float);      // 3.23 MB
    const size_t hb_off   = (pb_off + pb_bytes + 255) & ~(size_t)255;
    const size_t wb_off   = hb_off + (size_t)nH * 2;
    const size_t lb_off   = wb_off + (size_t)nWp * 2;                // ~115 MiB
    const size_t lb_bytes = (size_t)NROWS * VPAD * 2;                // 413 MB
    const size_t need_lb   = lb_off + lb_bytes;                      // ~528 MiB
    const size_t need_full = lb_off;                                 // ~115 MiB

    if (ws_size >= need_full) {
        __bf16* Hb = (__bf16*)((char*)d_ws + hb_off);
        __bf16* Wb = (__bf16*)((char*)d_ws + wb_off);
        float*  pb = (float*)((char*)d_ws + pb_off);
        cvt_bf16<<<(int)(nH / 8 / 256), 256, 0, stream>>>(H, Hb, nH, nH);
        cvt_bf16<<<(int)((nWp / 8 + 255) / 256), 256, 0, stream>>>(W, Wb, nW, nWp);
        if (ws_size >= need_lb) {
            __bf16* Lb = (__bf16*)((char*)d_ws + lb_off);
            gemm_fused<true><<<dim3(NWG), 512, 0, stream>>>(Hb, Wb, C, Lb, pb);
            lse_reduce<<<dim3(NROWS / 64), 256, 0, stream>>>(pb, lse);
            expand_sub<<<dim3(NROWS * 4), 256, 0, stream>>>(Lb, lse, C);
        } else {
            gemm_fused<false><<<dim3(NWG), 512, 0, stream>>>(Hb, Wb, C, (__bf16*)nullptr, pb);
            lse_reduce<<<dim3(NROWS / 64), 256, 0, stream>>>(pb, lse);
            sub_lse<<<dim3(NROWS), 256, 0, stream>>>(C, lse);
        }
    } else {
        dim3 ggrid(NROWS / FBM, (VOCAB + FBM - 1) / FBM);
        gemm_logits<<<ggrid, 256, 0, stream>>>(H, W, C);
        row_lse<<<dim3(NROWS), 256, 0, stream>>>(C, lse);
        sub_lse<<<dim3(NROWS), 256, 0, stream>>>(C, lse);
    }
}

// Round 18
// 851.757 us; speedup vs baseline: 1.1636x; 1.1636x over previous
//
#include <hip/hip_runtime.h>
#include <hip/hip_bf16.h>
#include <math.h>

#define VOCAB 50257
#define VPAD  50432          // VOCAB padded to multiple of 256
#define EMB   1024
#define NROWS 4096

#define BM 256
#define BN 256
#define BK 64
#define NKT (EMB / BK)       // 16
#define NMT (NROWS / BM)     // 16
#define NT  (VPAD / BN)      // 197
#define NWG (NMT * NT)       // 3152 (divisible by 8)

typedef __attribute__((ext_vector_type(4))) float  f32x4;
typedef __attribute__((ext_vector_type(16))) float f32x16;
typedef __attribute__((ext_vector_type(4), aligned(4))) float f32x4u;
typedef __attribute__((ext_vector_type(8))) __bf16 bf16x8;

#define FENCE asm volatile("" ::: "memory")
#define BARRIER do { FENCE; __builtin_amdgcn_s_barrier(); FENCE; } while (0)

// ---------------------------------------------------------------------------
// fp32 -> bf16 FRAGMENT-MAJOR convert:
// dst element layout: [panel][kt][unit = ks*8+rblk][lane(64)][e(8)]
//   row = panel*256 + rblk*32 + (lane&31)
//   k   = kt*64 + ks*16 + (lane>>5)*8 + e
// Writes linear/coalesced; reads are 64B-per-row gathers (L2-absorbed).
// One thread per 8 output elements. grid = panels*128 blocks exactly.
// ---------------------------------------------------------------------------
__global__ __launch_bounds__(256)
void cvt_frag(const float* __restrict__ src, __bf16* __restrict__ dst,
              int valid_rows) {
    const long o8 = (long)blockIdx.x * 256 + threadIdx.x;
    const int l    = (int)(o8 & 63);
    const int u    = (int)((o8 >> 6) & 31);
    const int kt   = (int)((o8 >> 11) & 15);
    const int pn   = (int)(o8 >> 15);
    const int ks   = u >> 3, rblk = u & 7;
    const int grow = pn * 256 + rblk * 32 + (l & 31);
    const int gk   = kt * 64 + ks * 16 + (l >> 5) * 8;
    bf16x8 v;
    if (grow < valid_rows) {
        const float* p = src + (size_t)grow * EMB + gk;
        f32x4 a = *(const f32x4*)p;
        f32x4 b = *(const f32x4*)(p + 4);
        #pragma unroll
        for (int e = 0; e < 4; ++e) {
            v[e]     = (__bf16)a[e];
            v[4 + e] = (__bf16)b[e];
        }
    } else {
        #pragma unroll
        for (int e = 0; e < 8; ++e) v[e] = (__bf16)0.0f;
    }
    *(bf16x8*)(dst + o8 * 8) = v;
}

// ---------------------------------------------------------------------------
// 256x256-tile bf16 GEMM, 32x32x16 MFMA, fragment-major LDS *and* source:
//   A/B workspaces pre-permuted (cvt_frag) so each global_load_lds reads
//   1024 contiguous bytes (src = unit_base + lane*16) AND every ds_read_b128
//   is linear base + lane*16 -> zero bank conflicts (R17-verified mapping).
// R15 skeleton: 4-phase interleave, 2 LDS buffers, stage calendar
// (4 loads ph0 / 2 ph1 / 2 ph2, vmcnt(4)), 8mt x 2nt chunk map, unroll x2.
// Fused sum-exp epilogue (stores first). C/D: col=lane&31,
// row=(reg&3)+8*(reg>>2)+4*(lane>>5)  [m74/m101-verified, R16/R17 refcheck'd].
// ---------------------------------------------------------------------------
template <bool LB_OUT>
__global__ __launch_bounds__(512, 2)
void gemm_fused(const __bf16* __restrict__ A, const __bf16* __restrict__ B,
                float* __restrict__ C, __bf16* __restrict__ Lb,
                float* __restrict__ pbuf) {
    __shared__ alignas(16) __bf16 S[65536];   // 128 KiB

    const int tid  = threadIdx.x;
    const int lane = tid & 63;
    const int wave = tid >> 6;
    const int wm   = (wave >> 2) * 128;       // 2 M-halves
    const int wn   = (wave & 3) * 64;         // 4 N-quarters
    const int l31  = lane & 31;
    const int h    = lane >> 5;

    // bijective XCD swizzle, then 8mt x 2nt chunks (<=6MB XCD-L2 hot window)
    const int b  = blockIdx.x;
    const int lg = (b & 7) * (NWG / 8) + (b >> 3);
    const int q  = lg >> 4, w = lg & 15;
    int mt, nt;
    if (q == 196) { mt = w; nt = 196; }
    else { mt = (q & 1) * 8 + (w & 7); nt = (q >> 1) * 2 + (w >> 3); }
    const int mtB = mt * BM, ntB = nt * BN;

    // fragment-major sources: panel bases + per-lane 16B offset
    const __bf16* gAf = A + (size_t)mt * (16 * 16384) + lane * 8;
    const __bf16* gBf = B + (size_t)nt * (16 * 16384) + lane * 8;

    f32x16 acc[4][2];
    #pragma unroll
    for (int mb = 0; mb < 4; ++mb)
        #pragma unroll
        for (int nb = 0; nb < 2; ++nb)
            #pragma unroll
            for (int e = 0; e < 16; ++e) acc[mb][nb][e] = 0.0f;

#define GLOAD(gp, dp)                                                         \
    __builtin_amdgcn_global_load_lds(                                         \
        (const __attribute__((address_space(1))) void*)(gp),                 \
        (__attribute__((address_space(3))) void*)(dp), 16, 0, 0)

    // stage unit (ks=u, rblk=wave) of K-tile kt: 1024B fully contiguous
#define STAGE_A(bc, kt, u)                                                    \
    GLOAD(gAf + ((size_t)(kt) * 32 + (u) * 8 + wave) * 512,                   \
          &S[(bc) * 32768 + ((u) * 8 + wave) * 512])

#define STAGE_B(bc, kt, u)                                                    \
    GLOAD(gBf + ((size_t)(kt) * 32 + (u) * 8 + wave) * 512,                   \
          &S[(bc) * 32768 + 16384 + ((u) * 8 + wave) * 512])

    // fragment reads: linear base + lane*16 (zero conflicts)
#define LDA32(dst, c, ks) { _Pragma("unroll")                                 \
    for (int mb_ = 0; mb_ < 4; ++mb_)                                         \
        dst[mb_] = *(const bf16x8*)&S[(c) * 32768                            \
            + (((ks) * 8) + ((wm >> 5) + mb_)) * 512 + lane * 8]; }

#define LDB32(dst, c, ks) { _Pragma("unroll")                                 \
    for (int nb_ = 0; nb_ < 2; ++nb_)                                         \
        dst[nb_] = *(const bf16x8*)&S[(c) * 32768 + 16384                    \
            + (((ks) * 8) + ((wn >> 5) + nb_)) * 512 + lane * 8]; }

#define MFMA8(AF, BF)                                                         \
    __builtin_amdgcn_s_setprio(1);                                            \
    _Pragma("unroll") for (int mb_ = 0; mb_ < 4; ++mb_)                       \
        _Pragma("unroll") for (int nb_ = 0; nb_ < 2; ++nb_)                   \
            acc[mb_][nb_] = __builtin_amdgcn_mfma_f32_32x32x16_bf16(          \
                AF[mb_], BF[nb_], acc[mb_][nb_], 0, 0, 0);                    \
    __builtin_amdgcn_s_setprio(0);

    bf16x8 afA[4], afB[4], bfrA[2], bfrB[2];

    // prologue: stage tile 0 into buf 0 (8 loads)
    #pragma unroll
    for (int u = 0; u < 4; ++u) { STAGE_A(0, 0, u); STAGE_B(0, 0, u); }

    #pragma unroll 2
    for (int t = 0; t < NKT; ++t) {
        const int c = t & 1;
        const bool pf = (t + 1 < NKT);
        // ---- phase 0 (ks0): stage 4 loads of t+1, wait tile t ----
        if (pf) {
            STAGE_A(c ^ 1, t + 1, 0); STAGE_B(c ^ 1, t + 1, 0);
            STAGE_A(c ^ 1, t + 1, 1); STAGE_B(c ^ 1, t + 1, 1);
            asm volatile("s_waitcnt vmcnt(4)" ::: "memory");  // tile t landed
        } else {
            asm volatile("s_waitcnt vmcnt(0)" ::: "memory");
        }
        BARRIER;
        LDB32(bfrA, c, 0); LDA32(afA, c, 0);
        LDB32(bfrB, c, 1); LDA32(afB, c, 1);   // ks1 fragments in flight
        MFMA8(afA, bfrA);
        // ---- phase 1 (ks1) ----
        if (pf) { STAGE_A(c ^ 1, t + 1, 2); STAGE_B(c ^ 1, t + 1, 2); }
        LDB32(bfrA, c, 2); LDA32(afA, c, 2);   // ks2 fragments in flight
        MFMA8(afB, bfrB);
        // ---- phase 2 (ks2) ----
        if (pf) { STAGE_A(c ^ 1, t + 1, 3); STAGE_B(c ^ 1, t + 1, 3); }
        LDB32(bfrB, c, 3); LDA32(afB, c, 3);   // ks3 fragments in flight
        MFMA8(afA, bfrA);
        // ---- phase 3 (ks3) ----
        MFMA8(afB, bfrB);
        BARRIER;                                // all waves done with buf c
    }
#undef STAGE_A
#undef STAGE_B
#undef GLOAD

    // ---------------- fused epilogue (stores first, sums under them) ------
    __syncthreads();                      // staging LDS reusable
    const bool edge = (ntB + BN > VOCAB); // only last nt tile

    if (LB_OUT) {
        #pragma unroll
        for (int mb = 0; mb < 4; ++mb) {
            #pragma unroll
            for (int r = 0; r < 16; ++r) {
                const int grow = mtB + wm + mb * 32 + (r & 3) + 8 * (r >> 2) + 4 * h;
                const size_t rb = (size_t)grow * VPAD + ntB + wn + l31;
                Lb[rb]      = (__bf16)acc[mb][0][r];
                Lb[rb + 32] = (__bf16)acc[mb][1][r];
            }
        }
    } else {
        #pragma unroll
        for (int mb = 0; mb < 4; ++mb) {
            #pragma unroll
            for (int r = 0; r < 16; ++r) {
                const int grow = mtB + wm + mb * 32 + (r & 3) + 8 * (r >> 2) + 4 * h;
                const size_t rb = (size_t)grow * VOCAB;
                const int col0 = ntB + wn + l31;
                if (!edge || col0 < VOCAB)      C[rb + col0]      = acc[mb][0][r];
                if (!edge || col0 + 32 < VOCAB) C[rb + col0 + 32] = acc[mb][1][r];
            }
        }
    }

    // per-lane exp-sums: fold cols via shfl_xor(16) -> LDS [256][68] f32
    float* ldsP = (float*)&S[0];
    const int col0 = ntB + wn + l31;
    #pragma unroll
    for (int mb = 0; mb < 4; ++mb) {
        #pragma unroll
        for (int r = 0; r < 16; ++r) {
            float s = 0.0f;
            if (!edge || col0 < VOCAB)      s += __expf(acc[mb][0][r]);
            if (!edge || col0 + 32 < VOCAB) s += __expf(acc[mb][1][r]);
            s += __shfl_xor(s, 16);
            if (l31 < 16) {
                const int lrow = wm + mb * 32 + (r & 3) + 8 * (r >> 2) + 4 * h;
                ldsP[lrow * 68 + (wave & 3) * 16 + (lane & 15)] = s;
            }
        }
    }
    __syncthreads();

    // reduce 64 partials per row -> pbuf[nt][global row]
    {
        const int rl = tid >> 1, hf = tid & 1;
        const float* q2 = ldsP + rl * 68 + hf * 32;
        float s = 0.0f;
        #pragma unroll
        for (int k = 0; k < 8; ++k) {
            f32x4 v = *(const f32x4*)(q2 + k * 4);
            s += v[0] + v[1] + v[2] + v[3];
        }
        s += __shfl_xor(s, 1);
        if (hf == 0) pbuf[(size_t)nt * NROWS + mtB + rl] = s;
    }
}

// ---------------------------------------------------------------------------
// reduce NT per-tile sumexp partials -> lse[row]; 64 rows per block
// ---------------------------------------------------------------------------
__global__ __launch_bounds__(256)
void lse_reduce(const float* __restrict__ pbuf, float* __restrict__ lse) {
    __shared__ float sl[4][64];
    const int r0 = blockIdx.x * 64;
    const int l  = threadIdx.x & 63;
    const int w  = threadIdx.x >> 6;
    float s = 0.0f;
    for (int t = w; t < NT; t += 4)
        s += pbuf[(size_t)t * NROWS + r0 + l];
    sl[w][l] = s;
    __syncthreads();
    if (threadIdx.x < 64)
        lse[r0 + l] = __logf(sl[0][l] + sl[1][l] + sl[2][l] + sl[3][l]);
}

// ---------------------------------------------------------------------------
// C[row][col] = (float)Lb[row][col] - lse[row]; 4 blocks per row (quarters),
// nontemporal load/store (read-once / write-once data).
// ---------------------------------------------------------------------------
__global__ __launch_bounds__(256)
void expand_sub(const __bf16* __restrict__ Lb, const float* __restrict__ lse,
                float* __restrict__ C) {
    const int row = blockIdx.x >> 2;
    const int q   = blockIdx.x & 3;
    const float s = lse[row];
    const __bf16* src = Lb + (size_t)row * VPAD;
    float* dst = C + (size_t)row * VOCAB;
    // 50257 = 8*6282 + 1; quarters of 1571 chunks (last quarter 1569 + tail)
    const int i0 = q * 1571;
    const int i1 = (q == 3) ? 6282 : i0 + 1571;
    for (int i = i0 + threadIdx.x; i < i1; i += 256) {
        bf16x8 v = __builtin_nontemporal_load((const bf16x8*)(src + i * 8));
        f32x4u a, b2;
        a[0] = (float)v[0] - s; a[1] = (float)v[1] - s;
        a[2] = (float)v[2] - s; a[3] = (float)v[3] - s;
        b2[0] = (float)v[4] - s; b2[1] = (float)v[5] - s;
        b2[2] = (float)v[6] - s; b2[3] = (float)v[7] - s;
        __builtin_nontemporal_store(a,  (f32x4u*)(dst + i * 8));
        __builtin_nontemporal_store(b2, (f32x4u*)(dst + i * 8 + 4));
    }
    if (q == 3 && threadIdx.x == 0)
        dst[50256] = (float)src[50256] - s;
}

// ---------------------------------------------------------------------------
// fallback fp32-input GEMM (128x128, R1 structure) + row LSE + sub if ws
// is too small for the workspace plan.
// ---------------------------------------------------------------------------
#define FBM 128
#define FBK 32
typedef __attribute__((ext_vector_type(4))) __bf16 bf16x4;
__device__ __forceinline__ int swz_idx(int row, int col) {
    int slot = (col >> 3) ^ ((row >> 1) & 3);
    return row * FBK + slot * 8 + (col & 7);
}

__global__ __launch_bounds__(256, 2)
void gemm_logits(const float* __restrict__ H, const float* __restrict__ W,
                 float* __restrict__ C) {
    __shared__ __bf16 ldsA[FBM * FBK];
    __shared__ __bf16 ldsB[FBM * FBK];

    const int tid  = threadIdx.x;
    const int lane = tid & 63;
    const int wave = tid >> 6;
    const int wm = (wave >> 1) * 64;
    const int wn = (wave & 1) * 64;
    const int mt = blockIdx.x;
    const int nt = blockIdx.y;
    const int srow = tid >> 1;
    const int scol = (tid & 1) * 16;
    const int brow_g = nt * FBM + srow;
    const bool bvalid = brow_g < VOCAB;
    const float* aptr = H + (size_t)(mt * FBM + srow) * EMB + scol;
    const float* bptr = W + (size_t)(bvalid ? brow_g : 0) * EMB + scol;

    f32x4 areg[4], breg[4];
    #pragma unroll
    for (int q = 0; q < 4; ++q) {
        areg[q] = *(const f32x4*)(aptr + q * 4);
        breg[q] = *(const f32x4*)(bptr + q * 4);
    }
    f32x4 acc[4][4];
    const f32x4 vzero = {0.f, 0.f, 0.f, 0.f};
    #pragma unroll
    for (int i = 0; i < 4; ++i)
        #pragma unroll
        for (int j = 0; j < 4; ++j) acc[i][j] = vzero;

    const int frow = lane & 15;
    const int kcol = (lane >> 4) * 8;

    for (int kt = 0; kt < EMB / FBK; ++kt) {
        __syncthreads();
        #pragma unroll
        for (int q = 0; q < 4; ++q) {
            const int col = scol + q * 4;
            bf16x4 av, bv;
            #pragma unroll
            for (int e = 0; e < 4; ++e) {
                av[e] = (__bf16)areg[q][e];
                bv[e] = bvalid ? (__bf16)breg[q][e] : (__bf16)0.0f;
            }
            *(bf16x4*)(&ldsA[swz_idx(srow, col)]) = av;
            *(bf16x4*)(&ldsB[swz_idx(srow, col)]) = bv;
        }
        __syncthreads();
        if (kt + 1 < EMB / FBK) {
            const int ko = (kt + 1) * FBK;
            #pragma unroll
            for (int q = 0; q < 4; ++q) {
                areg[q] = *(const f32x4*)(aptr + ko + q * 4);
                breg[q] = *(const f32x4*)(bptr + ko + q * 4);
            }
        }
        bf16x8 af[4], bfr[4];
        #pragma unroll
        for (int i = 0; i < 4; ++i) {
            af[i]  = *(const bf16x8*)(&ldsA[swz_idx(wm + i * 16 + frow, kcol)]);
            bfr[i] = *(const bf16x8*)(&ldsB[swz_idx(wn + i * 16 + frow, kcol)]);
        }
        #pragma unroll
        for (int i = 0; i < 4; ++i)
            #pragma unroll
            for (int j = 0; j < 4; ++j)
                acc[i][j] = __builtin_amdgcn_mfma_f32_16x16x32_bf16(
                    af[i], bfr[j], acc[i][j], 0, 0, 0);
    }

    const int crow = mt * FBM + wm + (lane >> 4) * 4;
    const int ccol = nt * FBM + wn + (lane & 15);
    #pragma unroll
    for (int i = 0; i < 4; ++i) {
        #pragma unroll
        for (int j = 0; j < 4; ++j) {
            const int col = ccol + j * 16;
            if (col < VOCAB) {
                #pragma unroll
                for (int r = 0; r < 4; ++r)
                    C[(size_t)(crow + i * 16 + r) * VOCAB + col] = acc[i][j][r];
            }
        }
    }
}

__global__ __launch_bounds__(256)
void row_lse(const float* __restrict__ C, float* __restrict__ lse) {
    const int row = blockIdx.x;
    const float* p = C + (size_t)row * VOCAB;

    float m = -INFINITY, l = 0.0f;
    for (int i = threadIdx.x; i < 12564; i += 256) {
        f32x4u v = *(const f32x4u*)(p + 4 * i);
        #pragma unroll
        for (int e = 0; e < 4; ++e) {
            const float x  = v[e];
            const float mn = fmaxf(m, x);
            l = l * __expf(m - mn) + __expf(x - mn);
            m = mn;
        }
    }
    if (threadIdx.x == 0) {
        const float x  = p[50256];
        const float mn = fmaxf(m, x);
        l = l * __expf(m - mn) + __expf(x - mn);
        m = mn;
    }
    #pragma unroll
    for (int off = 1; off < 64; off <<= 1) {
        const float mo = __shfl_xor(m, off);
        const float lo = __shfl_xor(l, off);
        const float mn = fmaxf(m, mo);
        l = l * __expf(m - mn) + lo * __expf(mo - mn);
        m = mn;
    }
    __shared__ float sm[4], sl[4];
    if ((threadIdx.x & 63) == 0) { sm[threadIdx.x >> 6] = m; sl[threadIdx.x >> 6] = l; }
    __syncthreads();
    if (threadIdx.x == 0) {
        m = sm[0]; l = sl[0];
        #pragma unroll
        for (int w = 1; w < 4; ++w) {
            const float mn = fmaxf(m, sm[w]);
            l = l * __expf(m - mn) + sl[w] * __expf(sm[w] - mn);
            m = mn;
        }
        lse[row] = m + __logf(l);
    }
}

__global__ __launch_bounds__(256)
void sub_lse(float* __restrict__ C, const float* __restrict__ lse) {
    const int row = blockIdx.x;
    const float s = lse[row];
    float* p = C + (size_t)row * VOCAB;
    for (int i = threadIdx.x; i < 12564; i += 256) {
        f32x4u v = *(const f32x4u*)(p + 4 * i);
        v[0] -= s; v[1] -= s; v[2] -= s; v[3] -= s;
        *(f32x4u*)(p + 4 * i) = v;
    }
    if (threadIdx.x == 0) p[50256] -= s;
}

// ---------------------------------------------------------------------------
extern "C" void kernel_launch(void* const* d_in, const int* in_sizes, int n_in,
                              void* d_out, int out_size, void* d_ws, size_t ws_size,
                              hipStream_t stream) {
    const float* H = (const float*)d_in[0];   // [4096][1024]
    const float* W = (const float*)d_in[1];   // [50257][1024]
    float* C   = (float*)d_out;               // [4096][50257]
    float* lse = (float*)d_ws;                // 4096 floats @ offset 0

    const long nH  = (long)NROWS * EMB;       // 4,194,304
    const long nWp = (long)VPAD * EMB;        // 51,642,368

    // layout: lse | pbuf | Hf | Wf | Lb
    const size_t pb_off   = 16384;
    const size_t pb_bytes = (size_t)NT * NROWS * sizeof(float);      // 3.23 MB
    const size_t hf_off   = (pb_off + pb_bytes + 255) & ~(size_t)255;
    const size_t wf_off   = hf_off + (size_t)nH * 2;
    const size_t lb_off   = wf_off + (size_t)nWp * 2;                // ~115 MiB
    const size_t lb_bytes = (size_t)NROWS * VPAD * 2;                // 413 MB
    const size_t need_lb   = lb_off + lb_bytes;                      // ~528 MiB
    const size_t need_full = lb_off;                                 // ~115 MiB

    if (ws_size >= need_full) {
        __bf16* Hf = (__bf16*)((char*)d_ws + hf_off);
        __bf16* Wf = (__bf16*)((char*)d_ws + wf_off);
        float*  pb = (float*)((char*)d_ws + pb_off);
        cvt_frag<<<dim3(NMT * 128), 256, 0, stream>>>(H, Hf, NROWS);
        cvt_frag<<<dim3(NT * 128),  256, 0, stream>>>(W, Wf, VOCAB);
        if (ws_size >= need_lb) {
            __bf16* Lb = (__bf16*)((char*)d_ws + lb_off);
            gemm_fused<true><<<dim3(NWG), 512, 0, stream>>>(Hf, Wf, C, Lb, pb);
            lse_reduce<<<dim3(NROWS / 64), 256, 0, stream>>>(pb, lse);
            expand_sub<<<dim3(NROWS * 4), 256, 0, stream>>>(Lb, lse, C);
        } else {
            gemm_fused<false><<<dim3(NWG), 512, 0, stream>>>(Hf, Wf, C, (__bf16*)nullptr, pb);
            lse_reduce<<<dim3(NROWS / 64), 256, 0, stream>>>(pb, lse);
            sub_lse<<<dim3(NROWS), 256, 0, stream>>>(C, lse);
        }
    } else {
        dim3 ggrid(NROWS / FBM, (VOCAB + FBM - 1) / FBM);
        gemm_logits<<<ggrid, 256, 0, stream>>>(H, W, C);
        row_lse<<<dim3(NROWS), 256, 0, stream>>>(C, lse);
        sub_lse<<<dim3(NROWS), 256, 0, stream>>>(C, lse);
    }
}

// Round 19
// 835.195 us; speedup vs baseline: 1.1867x; 1.0198x over previous
//
#include <hip/hip_runtime.h>
#include <hip/hip_bf16.h>
#include <math.h>

#define VOCAB 50257
#define VPAD  50432          // VOCAB padded to multiple of 256
#define EMB   1024
#define NROWS 4096

#define BM 256
#define BN 256
#define BK 32
#define NKT (EMB / BK)       // 32
#define NMT (NROWS / BM)     // 16
#define NT  (VPAD / BN)      // 197
#define NWG (NMT * NT)       // 3152 (divisible by 8)

typedef __attribute__((ext_vector_type(4))) float  f32x4;
typedef __attribute__((ext_vector_type(16))) float f32x16;
typedef __attribute__((ext_vector_type(4), aligned(4))) float f32x4u;
typedef __attribute__((ext_vector_type(8))) __bf16 bf16x8;

#define FENCE asm volatile("" ::: "memory")
#define BARRIER do { FENCE; __builtin_amdgcn_s_barrier(); FENCE; } while (0)
#define WAIT_LGKM do {                                                        \
        asm volatile("s_waitcnt lgkmcnt(0)" ::: "memory");                    \
        __builtin_amdgcn_sched_barrier(0);                                    \
    } while (0)

// ---------------------------------------------------------------------------
// fp32 -> bf16 fragment-major convert, LDS-tiled (coalesced both sides).
// Unit layout (BK=32): dst[((pn*32 + kt)*16 + ks*8 + rblk)*512 + lane*8 + e]
//   row = pn*256 + rblk*32 + (lane&31); k = kt*32 + ks*16 + (lane>>5)*8 + e.
// Block = (pn, rblk, kh): loads rows rblk*32..+32, cols kh*512..+512
// coalesced, emits 32 units (16 ktl x 2 ks) as contiguous 1KB writes.
// ---------------------------------------------------------------------------
__global__ __launch_bounds__(256)
void cvt_frag(const float* __restrict__ src, __bf16* __restrict__ dst,
              int valid_rows) {
    __shared__ __bf16 T[32][520];      // +8 pad: rows 16B-aligned, 4-way max
    const int bid  = blockIdx.x;
    const int kh   = bid & 1;
    const int rblk = (bid >> 1) & 7;
    const int pn   = bid >> 4;
    const int t    = threadIdx.x;
    const int row  = t >> 3;           // 0..31
    const int c0   = (t & 7) * 8;      // 0..56
    const int grow = pn * 256 + rblk * 32 + row;

    if (grow < valid_rows) {
        const float* p = src + (size_t)grow * EMB + kh * 512;
        #pragma unroll
        for (int it = 0; it < 8; ++it) {
            const int c = c0 + it * 64;
            f32x4 a = *(const f32x4*)(p + c);
            f32x4 b = *(const f32x4*)(p + c + 4);
            bf16x8 v;
            #pragma unroll
            for (int e = 0; e < 4; ++e) { v[e] = (__bf16)a[e]; v[4 + e] = (__bf16)b[e]; }
            *(bf16x8*)&T[row][c] = v;
        }
    } else {
        bf16x8 z;
        #pragma unroll
        for (int e = 0; e < 8; ++e) z[e] = (__bf16)0.0f;
        #pragma unroll
        for (int it = 0; it < 8; ++it) *(bf16x8*)&T[row][c0 + it * 64] = z;
    }
    __syncthreads();

    const int wv = t >> 6, l = t & 63;
    #pragma unroll
    for (int j = 0; j < 8; ++j) {
        const int u   = wv * 8 + j;    // 0..31
        const int ktl = u >> 1;        // 0..15
        const int ks  = u & 1;
        bf16x8 v = *(const bf16x8*)&T[l & 31][ktl * 32 + ks * 16 + (l >> 5) * 8];
        const size_t uo = ((size_t)(pn * 32 + kh * 16 + ktl) * 16 + ks * 8 + rblk) * 512;
        *(bf16x8*)(dst + uo + l * 8) = v;
    }
}

// ---------------------------------------------------------------------------
// 256x256-tile bf16 GEMM, 32x32x16 MFMA, fragment-major LDS+source,
// BK=32 / depth-2 prefetch (3 buffers, 96KB) / per-phase lockstep:
//   per tile: 2 phases x {6 ds_read || 2 gload(t+2) -> BAR -> lgkm(0) ->
//   setprio 8xMFMA setprio -> BAR}; vmcnt(4) once per tile (end), so the
//   issue->wait distance is 2 full tiles; vmcnt(0) only at the tail.
// Fused sum-exp epilogue (stores first). C/D layout m74/m101-verified.
// ---------------------------------------------------------------------------
template <bool LB_OUT>
__global__ __launch_bounds__(512, 2)
void gemm_fused(const __bf16* __restrict__ A, const __bf16* __restrict__ B,
                float* __restrict__ C, __bf16* __restrict__ Lb,
                float* __restrict__ pbuf) {
    __shared__ alignas(16) __bf16 S[49152];   // 3 x 32KB

    const int tid  = threadIdx.x;
    const int lane = tid & 63;
    const int wave = tid >> 6;
    const int wm   = (wave >> 2) * 128;       // 2 M-halves
    const int wn   = (wave & 3) * 64;         // 4 N-quarters
    const int l31  = lane & 31;
    const int h    = lane >> 5;

    // bijective XCD swizzle, then 8mt x 2nt chunks
    const int b  = blockIdx.x;
    const int lg = (b & 7) * (NWG / 8) + (b >> 3);
    const int q  = lg >> 4, w = lg & 15;
    int mt, nt;
    if (q == 196) { mt = w; nt = 196; }
    else { mt = (q & 1) * 8 + (w & 7); nt = (q >> 1) * 2 + (w >> 3); }
    const int mtB = mt * BM, ntB = nt * BN;

    // fragment-major panel bases + per-lane 16B offset
    const __bf16* gAf = A + (size_t)mt * (NKT * 16 * 512) + lane * 8;
    const __bf16* gBf = B + (size_t)nt * (NKT * 16 * 512) + lane * 8;

    f32x16 acc[4][2];
    #pragma unroll
    for (int mb = 0; mb < 4; ++mb)
        #pragma unroll
        for (int nb = 0; nb < 2; ++nb)
            #pragma unroll
            for (int e = 0; e < 16; ++e) acc[mb][nb][e] = 0.0f;

#define GLOAD(gp, dp)                                                         \
    __builtin_amdgcn_global_load_lds(                                         \
        (const __attribute__((address_space(1))) void*)(gp),                 \
        (__attribute__((address_space(3))) void*)(dp), 16, 0, 0)

    // stage unit (ks=u, rblk=wave) of K-tile kt into buffer bc
#define STAGE_A(bc, kt, u)                                                    \
    GLOAD(gAf + ((size_t)(kt) * 16 + (u) * 8 + wave) * 512,                   \
          &S[(bc) * 16384 + ((u) * 8 + wave) * 512])

#define STAGE_B(bc, kt, u)                                                    \
    GLOAD(gBf + ((size_t)(kt) * 16 + (u) * 8 + wave) * 512,                   \
          &S[(bc) * 16384 + 8192 + ((u) * 8 + wave) * 512])

    // fragment reads: linear base + lane*16 (zero conflicts)
#define LDA32(dst, c, ks) { _Pragma("unroll")                                 \
    for (int mb_ = 0; mb_ < 4; ++mb_)                                         \
        dst[mb_] = *(const bf16x8*)&S[(c) * 16384                            \
            + (((ks) * 8) + ((wm >> 5) + mb_)) * 512 + lane * 8]; }

#define LDB32(dst, c, ks) { _Pragma("unroll")                                 \
    for (int nb_ = 0; nb_ < 2; ++nb_)                                         \
        dst[nb_] = *(const bf16x8*)&S[(c) * 16384 + 8192                     \
            + (((ks) * 8) + ((wn >> 5) + nb_)) * 512 + lane * 8]; }

#define MFMA8(AF, BF)                                                         \
    __builtin_amdgcn_s_setprio(1);                                            \
    _Pragma("unroll") for (int mb_ = 0; mb_ < 4; ++mb_)                       \
        _Pragma("unroll") for (int nb_ = 0; nb_ < 2; ++nb_)                   \
            acc[mb_][nb_] = __builtin_amdgcn_mfma_f32_32x32x16_bf16(          \
                AF[mb_], BF[nb_], acc[mb_][nb_], 0, 0, 0);                    \
    __builtin_amdgcn_s_setprio(0);

    bf16x8 afA[4], afB[4], bfrA[2], bfrB[2];

    // prologue: tile0 -> buf0 (4/wave), tile1 -> buf1 (4/wave)
    STAGE_A(0, 0, 0); STAGE_B(0, 0, 0); STAGE_A(0, 0, 1); STAGE_B(0, 0, 1);
    STAGE_A(1, 1, 0); STAGE_B(1, 1, 0); STAGE_A(1, 1, 1); STAGE_B(1, 1, 1);
    asm volatile("s_waitcnt vmcnt(4)" ::: "memory");   // tile0 landed
    BARRIER;

    int c = 0;
    for (int t = 0; t < NKT; ++t) {
        const int n  = (c == 0) ? 2 : c - 1;            // (c+2)%3
        const bool p1 = (t + 1 < NKT);
        const bool p2 = (t + 2 < NKT);

        // ---- phase 0 (ks0) ----
        LDB32(bfrA, c, 0); LDA32(afA, c, 0);
        if (p2) { STAGE_A(n, t + 2, 0); STAGE_B(n, t + 2, 0); }
        BARRIER;
        WAIT_LGKM;
        MFMA8(afA, bfrA);
        BARRIER;
        // ---- phase 1 (ks1) ----
        LDB32(bfrB, c, 1); LDA32(afB, c, 1);
        if (p2) { STAGE_A(n, t + 2, 1); STAGE_B(n, t + 2, 1); }
        if (p1) {
            if (p2) asm volatile("s_waitcnt vmcnt(4)" ::: "memory"); // t+1 landed
            else    asm volatile("s_waitcnt vmcnt(0)" ::: "memory");
        }
        BARRIER;
        WAIT_LGKM;
        MFMA8(afB, bfrB);
        BARRIER;

        c = (c == 2) ? 0 : c + 1;
    }
#undef STAGE_A
#undef STAGE_B
#undef GLOAD

    // ---------------- fused epilogue (stores first, sums under them) ------
    __syncthreads();                      // staging LDS reusable
    const bool edge = (ntB + BN > VOCAB); // only last nt tile

    if (LB_OUT) {
        #pragma unroll
        for (int mb = 0; mb < 4; ++mb) {
            #pragma unroll
            for (int r = 0; r < 16; ++r) {
                const int grow = mtB + wm + mb * 32 + (r & 3) + 8 * (r >> 2) + 4 * h;
                const size_t rb = (size_t)grow * VPAD + ntB + wn + l31;
                Lb[rb]      = (__bf16)acc[mb][0][r];
                Lb[rb + 32] = (__bf16)acc[mb][1][r];
            }
        }
    } else {
        #pragma unroll
        for (int mb = 0; mb < 4; ++mb) {
            #pragma unroll
            for (int r = 0; r < 16; ++r) {
                const int grow = mtB + wm + mb * 32 + (r & 3) + 8 * (r >> 2) + 4 * h;
                const size_t rb = (size_t)grow * VOCAB;
                const int col0 = ntB + wn + l31;
                if (!edge || col0 < VOCAB)      C[rb + col0]      = acc[mb][0][r];
                if (!edge || col0 + 32 < VOCAB) C[rb + col0 + 32] = acc[mb][1][r];
            }
        }
    }

    // per-lane exp-sums: fold cols via shfl_xor(16) -> LDS [256][68] f32
    float* ldsP = (float*)&S[0];
    const int col0 = ntB + wn + l31;
    #pragma unroll
    for (int mb = 0; mb < 4; ++mb) {
        #pragma unroll
        for (int r = 0; r < 16; ++r) {
            float s = 0.0f;
            if (!edge || col0 < VOCAB)      s += __expf(acc[mb][0][r]);
            if (!edge || col0 + 32 < VOCAB) s += __expf(acc[mb][1][r]);
            s += __shfl_xor(s, 16);
            if (l31 < 16) {
                const int lrow = wm + mb * 32 + (r & 3) + 8 * (r >> 2) + 4 * h;
                ldsP[lrow * 68 + (wave & 3) * 16 + (lane & 15)] = s;
            }
        }
    }
    __syncthreads();

    // reduce 64 partials per row -> pbuf[nt][global row]
    {
        const int rl = tid >> 1, hf = tid & 1;
        const float* q2 = ldsP + rl * 68 + hf * 32;
        float s = 0.0f;
        #pragma unroll
        for (int k = 0; k < 8; ++k) {
            f32x4 v = *(const f32x4*)(q2 + k * 4);
            s += v[0] + v[1] + v[2] + v[3];
        }
        s += __shfl_xor(s, 1);
        if (hf == 0) pbuf[(size_t)nt * NROWS + mtB + rl] = s;
    }
}

// ---------------------------------------------------------------------------
// reduce NT per-tile sumexp partials -> lse[row]; 64 rows per block
// ---------------------------------------------------------------------------
__global__ __launch_bounds__(256)
void lse_reduce(const float* __restrict__ pbuf, float* __restrict__ lse) {
    __shared__ float sl[4][64];
    const int r0 = blockIdx.x * 64;
    const int l  = threadIdx.x & 63;
    const int w  = threadIdx.x >> 6;
    float s = 0.0f;
    for (int t = w; t < NT; t += 4)
        s += pbuf[(size_t)t * NROWS + r0 + l];
    sl[w][l] = s;
    __syncthreads();
    if (threadIdx.x < 64)
        lse[r0 + l] = __logf(sl[0][l] + sl[1][l] + sl[2][l] + sl[3][l]);
}

// ---------------------------------------------------------------------------
// C[row][col] = (float)Lb[row][col] - lse[row]; 4 blocks per row,
// nontemporal load/store (read-once / write-once data).
// ---------------------------------------------------------------------------
__global__ __launch_bounds__(256)
void expand_sub(const __bf16* __restrict__ Lb, const float* __restrict__ lse,
                float* __restrict__ C) {
    const int row = blockIdx.x >> 2;
    const int q   = blockIdx.x & 3;
    const float s = lse[row];
    const __bf16* src = Lb + (size_t)row * VPAD;
    float* dst = C + (size_t)row * VOCAB;
    const int i0 = q * 1571;
    const int i1 = (q == 3) ? 6282 : i0 + 1571;
    for (int i = i0 + threadIdx.x; i < i1; i += 256) {
        bf16x8 v = __builtin_nontemporal_load((const bf16x8*)(src + i * 8));
        f32x4u a, b2;
        a[0] = (float)v[0] - s; a[1] = (float)v[1] - s;
        a[2] = (float)v[2] - s; a[3] = (float)v[3] - s;
        b2[0] = (float)v[4] - s; b2[1] = (float)v[5] - s;
        b2[2] = (float)v[6] - s; b2[3] = (float)v[7] - s;
        __builtin_nontemporal_store(a,  (f32x4u*)(dst + i * 8));
        __builtin_nontemporal_store(b2, (f32x4u*)(dst + i * 8 + 4));
    }
    if (q == 3 && threadIdx.x == 0)
        dst[50256] = (float)src[50256] - s;
}

// ---------------------------------------------------------------------------
// fallback fp32-input GEMM (128x128, R1 structure) + row LSE + sub
// ---------------------------------------------------------------------------
#define FBM 128
#define FBK 32
typedef __attribute__((ext_vector_type(4))) __bf16 bf16x4;
__device__ __forceinline__ int swz_idx(int row, int col) {
    int slot = (col >> 3) ^ ((row >> 1) & 3);
    return row * FBK + slot * 8 + (col & 7);
}

__global__ __launch_bounds__(256, 2)
void gemm_logits(const float* __restrict__ H, const float* __restrict__ W,
                 float* __restrict__ C) {
    __shared__ __bf16 ldsA[FBM * FBK];
    __shared__ __bf16 ldsB[FBM * FBK];

    const int tid  = threadIdx.x;
    const int lane = tid & 63;
    const int wave = tid >> 6;
    const int wm = (wave >> 1) * 64;
    const int wn = (wave & 1) * 64;
    const int mt = blockIdx.x;
    const int nt = blockIdx.y;
    const int srow = tid >> 1;
    const int scol = (tid & 1) * 16;
    const int brow_g = nt * FBM + srow;
    const bool bvalid = brow_g < VOCAB;
    const float* aptr = H + (size_t)(mt * FBM + srow) * EMB + scol;
    const float* bptr = W + (size_t)(bvalid ? brow_g : 0) * EMB + scol;

    f32x4 areg[4], breg[4];
    #pragma unroll
    for (int q = 0; q < 4; ++q) {
        areg[q] = *(const f32x4*)(aptr + q * 4);
        breg[q] = *(const f32x4*)(bptr + q * 4);
    }
    f32x4 acc[4][4];
    const f32x4 vzero = {0.f, 0.f, 0.f, 0.f};
    #pragma unroll
    for (int i = 0; i < 4; ++i)
        #pragma unroll
        for (int j = 0; j < 4; ++j) acc[i][j] = vzero;

    const int frow = lane & 15;
    const int kcol = (lane >> 4) * 8;

    for (int kt = 0; kt < EMB / FBK; ++kt) {
        __syncthreads();
        #pragma unroll
        for (int q = 0; q < 4; ++q) {
            const int col = scol + q * 4;
            bf16x4 av, bv;
            #pragma unroll
            for (int e = 0; e < 4; ++e) {
                av[e] = (__bf16)areg[q][e];
                bv[e] = bvalid ? (__bf16)breg[q][e] : (__bf16)0.0f;
            }
            *(bf16x4*)(&ldsA[swz_idx(srow, col)]) = av;
            *(bf16x4*)(&ldsB[swz_idx(srow, col)]) = bv;
        }
        __syncthreads();
        if (kt + 1 < EMB / FBK) {
            const int ko = (kt + 1) * FBK;
            #pragma unroll
            for (int q = 0; q < 4; ++q) {
                areg[q] = *(const f32x4*)(aptr + ko + q * 4);
                breg[q] = *(const f32x4*)(bptr + ko + q * 4);
            }
        }
        bf16x8 af[4], bfr[4];
        #pragma unroll
        for (int i = 0; i < 4; ++i) {
            af[i]  = *(const bf16x8*)(&ldsA[swz_idx(wm + i * 16 + frow, kcol)]);
            bfr[i] = *(const bf16x8*)(&ldsB[swz_idx(wn + i * 16 + frow, kcol)]);
        }
        #pragma unroll
        for (int i = 0; i < 4; ++i)
            #pragma unroll
            for (int j = 0; j < 4; ++j)
                acc[i][j] = __builtin_amdgcn_mfma_f32_16x16x32_bf16(
                    af[i], bfr[j], acc[i][j], 0, 0, 0);
    }

    const int crow = mt * FBM + wm + (lane >> 4) * 4;
    const int ccol = nt * FBM + wn + (lane & 15);
    #pragma unroll
    for (int i = 0; i < 4; ++i) {
        #pragma unroll
        for (int j = 0; j < 4; ++j) {
            const int col = ccol + j * 16;
            if (col < VOCAB) {
                #pragma unroll
                for (int r = 0; r < 4; ++r)
                    C[(size_t)(crow + i * 16 + r) * VOCAB + col] = acc[i][j][r];
            }
        }
    }
}

__global__ __launch_bounds__(256)
void row_lse(const float* __restrict__ C, float* __restrict__ lse) {
    const int row = blockIdx.x;
    const float* p = C + (size_t)row * VOCAB;

    float m = -INFINITY, l = 0.0f;
    for (int i = threadIdx.x; i < 12564; i += 256) {
        f32x4u v = *(const f32x4u*)(p + 4 * i);
        #pragma unroll
        for (int e = 0; e < 4; ++e) {
            const float x  = v[e];
            const float mn = fmaxf(m, x);
            l = l * __expf(m - mn) + __expf(x - mn);
            m = mn;
        }
    }
    if (threadIdx.x == 0) {
        const float x  = p[50256];
        const float mn = fmaxf(m, x);
        l = l * __expf(m - mn) + __expf(x - mn);
        m = mn;
    }
    #pragma unroll
    for (int off = 1; off < 64; off <<= 1) {
        const float mo = __shfl_xor(m, off);
        const float lo = __shfl_xor(l, off);
        const float mn = fmaxf(m, mo);
        l = l * __expf(m - mn) + lo * __expf(mo - mn);
        m = mn;
    }
    __shared__ float sm[4], sl[4];
    if ((threadIdx.x & 63) == 0) { sm[threadIdx.x >> 6] = m; sl[threadIdx.x >> 6] = l; }
    __syncthreads();
    if (threadIdx.x == 0) {
        m = sm[0]; l = sl[0];
        #pragma unroll
        for (int w = 1; w < 4; ++w) {
            const float mn = fmaxf(m, sm[w]);
            l = l * __expf(m - mn) + sl[w] * __expf(sm[w] - mn);
            m = mn;
        }
        lse[row] = m + __logf(l);
    }
}

__global__ __launch_bounds__(256)
void sub_lse(float* __restrict__ C, const float* __restrict__ lse) {
    const int row = blockIdx.x;
    const float s = lse[row];
    float* p = C + (size_t)row * VOCAB;
    for (int i = threadIdx.x; i < 12564; i += 256) {
        f32x4u v = *(const f32x4u*)(p + 4 * i);
        v[0] -= s; v[1] -= s; v[2] -= s; v[3] -= s;
        *(f32x4u*)(p + 4 * i) = v;
    }
    if (threadIdx.x == 0) p[50256] -= s;
}

// ---------------------------------------------------------------------------
extern "C" void kernel_launch(void* const* d_in, const int* in_sizes, int n_in,
                              void* d_out, int out_size, void* d_ws, size_t ws_size,
                              hipStream_t stream) {
    const float* H = (const float*)d_in[0];   // [4096][1024]
    const float* W = (const float*)d_in[1];   // [50257][1024]
    float* C   = (float*)d_out;               // [4096][50257]
    float* lse = (float*)d_ws;                // 4096 floats @ offset 0

    const long nH  = (long)NROWS * EMB;       // 4,194,304
    const long nWp = (long)VPAD * EMB;        // 51,642,368

    // layout: lse | pbuf | Hf | Wf | Lb
    const size_t pb_off   = 16384;
    const size_t pb_bytes = (size_t)NT * NROWS * sizeof(float);      // 3.23 MB
    const size_t hf_off   = (pb_off + pb_bytes + 255) & ~(size_t)255;
    const size_t wf_off   = hf_off + (size_t)nH * 2;
    const size_t lb_off   = wf_off + (size_t)nWp * 2;                // ~115 MiB
    const size_t lb_bytes = (size_t)NROWS * VPAD * 2;                // 413 MB
    const size_t need_lb   = lb_off + lb_bytes;                      // ~528 MiB
    const size_t need_full = lb_off;                                 // ~115 MiB

    if (ws_size >= need_full) {
        __bf16* Hf = (__bf16*)((char*)d_ws + hf_off);
        __bf16* Wf = (__bf16*)((char*)d_ws + wf_off);
        float*  pb = (float*)((char*)d_ws + pb_off);
        cvt_frag<<<dim3(NMT * 16), 256, 0, stream>>>(H, Hf, NROWS);
        cvt_frag<<<dim3(NT * 16),  256, 0, stream>>>(W, Wf, VOCAB);
        if (ws_size >= need_lb) {
            __bf16* Lb = (__bf16*)((char*)d_ws + lb_off);
            gemm_fused<true><<<dim3(NWG), 512, 0, stream>>>(Hf, Wf, C, Lb, pb);
            lse_reduce<<<dim3(NROWS / 64), 256, 0, stream>>>(pb, lse);
            expand_sub<<<dim3(NROWS * 4), 256, 0, stream>>>(Lb, lse, C);
        } else {
            gemm_fused<false><<<dim3(NWG), 512, 0, stream>>>(Hf, Wf, C, (__bf16*)nullptr, pb);
            lse_reduce<<<dim3(NROWS / 64), 256, 0, stream>>>(pb, lse);
            sub_lse<<<dim3(NROWS), 256, 0, stream>>>(C, lse);
        }
    } else {
        dim3 ggrid(NROWS / FBM, (VOCAB + FBM - 1) / FBM);
        gemm_logits<<<ggrid, 256, 0, stream>>>(H, W, C);
        row_lse<<<dim3(NROWS), 256, 0, stream>>>(C, lse);
        sub_lse<<<dim3(NROWS), 256, 0, stream>>>(C, lse);
    }
}

// Round 20
// 787.830 us; speedup vs baseline: 1.2580x; 1.0601x over previous
//
#include <hip/hip_runtime.h>
#include <hip/hip_bf16.h>
#include <math.h>

#define VOCAB 50257
#define VPAD  50432          // VOCAB padded to multiple of 256
#define EMB   1024
#define NROWS 4096

#define BM 256
#define BN 256
#define BK 64
#define NKT (EMB / BK)       // 16
#define NMT (NROWS / BM)     // 16
#define NT  (VPAD / BN)      // 197
#define NWG (NMT * NT)       // 3152 (divisible by 8)

typedef __attribute__((ext_vector_type(4))) float  f32x4;
typedef __attribute__((ext_vector_type(4), aligned(4))) float f32x4u;
typedef __attribute__((ext_vector_type(4))) __bf16 bf16x4;
typedef __attribute__((ext_vector_type(8))) __bf16 bf16x8;

#define FENCE asm volatile("" ::: "memory")
#define BARRIER do { FENCE; __builtin_amdgcn_s_barrier(); FENCE; } while (0)

// ---------------------------------------------------------------------------
// fp32 -> bf16 convert (pads tail with zeros). n_src, n_dst multiples of 8.
// ---------------------------------------------------------------------------
__global__ __launch_bounds__(256)
void cvt_bf16(const float* __restrict__ src, __bf16* __restrict__ dst,
              long n_src, long n_dst) {
    long i = ((long)blockIdx.x * 256 + threadIdx.x) * 8;
    if (i >= n_dst) return;
    bf16x8 o;
    if (i < n_src) {
        f32x4 a = *(const f32x4*)(src + i);
        f32x4 b = *(const f32x4*)(src + i + 4);
        #pragma unroll
        for (int e = 0; e < 4; ++e) {
            o[e]     = (__bf16)a[e];
            o[4 + e] = (__bf16)b[e];
        }
    } else {
        #pragma unroll
        for (int e = 0; e < 8; ++e) o[e] = (__bf16)0.0f;
    }
    *(bf16x8*)(dst + i) = o;
}

// ---------------------------------------------------------------------------
// 256x256-tile bf16 GEMM (R12 skeleton: 4-phase fine interleave, 2 LDS
// buffers, source-order pipelined ds_reads) with:
//  - shifted stage calendar: u0+u1 of t+1 at ph0 (vmcnt(4)), u2 ph1, u3 ph2
//  - 8mt x 2nt chunk mapping for XCD-L2 working-set reduction
//  - K-loop unrolled x2
// Fused sum-exp epilogue; Lb stores first, exp/reduce drains under them.
// LB_OUT=1: bf16 logits -> Lb[row][VPAD]; LB_OUT=0: f32 -> C (fallback).
// ---------------------------------------------------------------------------
template <bool LB_OUT>
__global__ __launch_bounds__(512, 2)
void gemm_fused(const __bf16* __restrict__ A, const __bf16* __restrict__ B,
                float* __restrict__ C, __bf16* __restrict__ Lb,
                float* __restrict__ pbuf) {
    __shared__ alignas(16) __bf16 S[65536];   // 128 KiB

    const int tid  = threadIdx.x;
    const int lane = tid & 63;
    const int wave = tid >> 6;
    const int wm   = (wave >> 2) * 128;       // 2 M-halves
    const int wn   = (wave & 3) * 64;         // 4 N-quarters
    const int frow = lane & 15;
    const int hi   = lane >> 4;

    // bijective XCD swizzle, then 8mt x 2nt chunks (keeps <=6MB hot window
    // on the 4MB XCD L2 vs 8.5MB for m-fastest columns)
    const int b  = blockIdx.x;
    const int lg = (b & 7) * (NWG / 8) + (b >> 3);
    const int q  = lg >> 4, w = lg & 15;
    int mt, nt;
    if (q == 196) { mt = w; nt = 196; }                        // last nt column
    else { mt = (q & 1) * 8 + (w & 7); nt = (q >> 1) * 2 + (w >> 3); }
    const int mtB = mt * BM, ntB = nt * BN;

    const int r0 = tid >> 3;
    const int ls = (tid & 7) ^ (r0 & 7);
    const __bf16* gA = A + (size_t)(mtB + r0) * EMB + ls * 8;
    const __bf16* gB = B + (size_t)(ntB + r0) * EMB + ls * 8;

    f32x4 acc[8][4];
    const f32x4 vzero = {0.f, 0.f, 0.f, 0.f};
    #pragma unroll
    for (int m = 0; m < 8; ++m)
        #pragma unroll
        for (int n = 0; n < 4; ++n) acc[m][n] = vzero;

    // unit u: 0 = B rows 0-127, 1 = B rows 128-255, 2 = A half0, 3 = A half1
#define STAGE_UNIT(bc, kt, u) do {                                            \
        const __bf16* g_ = ((u) < 2 ? gB : gA) + ((size_t)(((u)&1) * 128) * EMB + (kt) * BK); \
        __bf16* d_ = &S[(bc) * 32768 + ((u) < 2 ? 16384 : 0) + ((u)&1) * 8192 + wave * 512]; \
        __builtin_amdgcn_global_load_lds(                                     \
            (const __attribute__((address_space(1))) void*)g_,               \
            (__attribute__((address_space(3))) void*)d_, 16, 0, 0);          \
        __builtin_amdgcn_global_load_lds(                                     \
            (const __attribute__((address_space(1))) void*)(g_ + (size_t)64 * EMB), \
            (__attribute__((address_space(3))) void*)(d_ + 4096), 16, 0, 0); \
    } while (0)

#define LDA_TO(dst, c, mh, ks) { _Pragma("unroll")                            \
    for (int i_ = 0; i_ < 4; ++i_) {                                          \
        const int row_ = wm + ((mh) * 4 + i_) * 16 + frow;                    \
        dst[i_] = *(const bf16x8*)&S[(c) * 32768 + row_ * 64 + ((((ks) * 4 + hi)) ^ (row_ & 7)) * 8]; } }

#define LDB_TO(dst, c, ks) { _Pragma("unroll")                                \
    for (int n_ = 0; n_ < 4; ++n_) {                                          \
        const int row_ = wn + n_ * 16 + frow;                                 \
        dst[n_] = *(const bf16x8*)&S[(c) * 32768 + 16384 + row_ * 64 + ((((ks) * 4 + hi)) ^ (row_ & 7)) * 8]; } }

#define MFMA16(mh, AF, BF)                                                    \
    __builtin_amdgcn_s_setprio(1);                                            \
    _Pragma("unroll") for (int i_ = 0; i_ < 4; ++i_)                          \
        _Pragma("unroll") for (int n_ = 0; n_ < 4; ++n_)                      \
            acc[(mh) * 4 + i_][n_] = __builtin_amdgcn_mfma_f32_16x16x32_bf16( \
                AF[i_], BF[n_], acc[(mh) * 4 + i_][n_], 0, 0, 0);             \
    __builtin_amdgcn_s_setprio(0);

    bf16x8 afA[4], afB[4], bfrA[4], bfrB[4];

    // prologue: stage tile 0 into buf 0
    #pragma unroll
    for (int u = 0; u < 4; ++u) STAGE_UNIT(0, 0, u);

    #pragma unroll 2
    for (int t = 0; t < NKT; ++t) {
        const int c = t & 1;
        const bool pf = (t + 1 < NKT);
        // ---- phase 0: stage u0+u1 of t+1, wait tile t, compute (ks0,mh0) --
        if (pf) {
            STAGE_UNIT(c ^ 1, t + 1, 0);
            STAGE_UNIT(c ^ 1, t + 1, 1);
            asm volatile("s_waitcnt vmcnt(4)" ::: "memory");  // tile t landed
        } else {
            asm volatile("s_waitcnt vmcnt(0)" ::: "memory");
        }
        BARRIER;
        LDB_TO(bfrA, c, 0);
        LDA_TO(afA, c, 0, 0);
        LDA_TO(afB, c, 1, 0);            // phase-1 fragments in flight
        MFMA16(0, afA, bfrA);
        // ---- phase 1 ----
        if (pf) STAGE_UNIT(c ^ 1, t + 1, 2);
        LDB_TO(bfrB, c, 1);              // phase-2/3 fragments in flight
        LDA_TO(afA, c, 0, 1);
        MFMA16(1, afB, bfrA);
        // ---- phase 2 ----
        if (pf) STAGE_UNIT(c ^ 1, t + 1, 3);
        LDA_TO(afB, c, 1, 1);            // phase-3 fragments in flight
        MFMA16(0, afA, bfrB);
        // ---- phase 3 (no staging: u3 issued a phase earlier) ----
        MFMA16(1, afB, bfrB);
        BARRIER;                          // all waves done reading buf c
    }
#undef STAGE_UNIT

    // ---------------- fused epilogue (stores first, sums under them) ------
    __syncthreads();                      // staging LDS reusable
    const bool edge = (ntB + BN > VOCAB); // only last nt tile

    if (LB_OUT) {
        #pragma unroll
        for (int m = 0; m < 8; ++m) {
            const size_t rbase = (size_t)(mtB + wm + m * 16 + hi * 4) * VPAD;
            #pragma unroll
            for (int n = 0; n < 4; ++n) {
                const size_t col = ntB + wn + n * 16 + frow;
                #pragma unroll
                for (int r = 0; r < 4; ++r)
                    Lb[rbase + (size_t)r * VPAD + col] = (__bf16)acc[m][n][r];
            }
        }
    } else {
        #pragma unroll
        for (int m = 0; m < 8; ++m) {
            const size_t rbase = (size_t)(mtB + wm + m * 16 + hi * 4) * VOCAB;
            #pragma unroll
            for (int n = 0; n < 4; ++n) {
                const int col = ntB + wn + n * 16 + frow;
                if (!edge || col < VOCAB) {
                    #pragma unroll
                    for (int r = 0; r < 4; ++r)
                        C[rbase + (size_t)r * VOCAB + col] = acc[m][n][r];
                }
            }
        }
    }

    // per-lane exp-sums -> LDS transpose buffer [256 rows][68] f32 (68 KB);
    // these VALU/LDS ops drain while the stores above are in flight
    float* ldsP = (float*)&S[0];
    const int lcid = (wave & 3) * 16 + frow;   // 0..63 column-group id
    #pragma unroll
    for (int m = 0; m < 8; ++m) {
        #pragma unroll
        for (int r = 0; r < 4; ++r) {
            float s = 0.0f;
            #pragma unroll
            for (int n = 0; n < 4; ++n) {
                if (!edge || (ntB + wn + n * 16 + frow) < VOCAB)
                    s += __expf(acc[m][n][r]);
            }
            ldsP[(wm + m * 16 + hi * 4 + r) * 68 + lcid] = s;
        }
    }
    __syncthreads();

    // reduce 64 partials per row -> pbuf[nt][global row]
    {
        const int rl = tid >> 1, hf = tid & 1;
        const float* q2 = ldsP + rl * 68 + hf * 32;
        float s = 0.0f;
        #pragma unroll
        for (int k = 0; k < 8; ++k) {
            f32x4 v = *(const f32x4*)(q2 + k * 4);
            s += v[0] + v[1] + v[2] + v[3];
        }
        s += __shfl_xor(s, 1);
        if (hf == 0) pbuf[(size_t)nt * NROWS + mtB + rl] = s;
    }
}

// ---------------------------------------------------------------------------
// reduce NT per-tile sumexp partials -> lse[row]; 64 rows per block
// ---------------------------------------------------------------------------
__global__ __launch_bounds__(256)
void lse_reduce(const float* __restrict__ pbuf, float* __restrict__ lse) {
    __shared__ float sl[4][64];
    const int r0 = blockIdx.x * 64;
    const int l  = threadIdx.x & 63;
    const int w  = threadIdx.x >> 6;
    float s = 0.0f;
    for (int t = w; t < NT; t += 4)
        s += pbuf[(size_t)t * NROWS + r0 + l];
    sl[w][l] = s;
    __syncthreads();
    if (threadIdx.x < 64)
        lse[r0 + l] = __logf(sl[0][l] + sl[1][l] + sl[2][l] + sl[3][l]);
}

// ---------------------------------------------------------------------------
// C[row][col] = (float)Lb[row][col] - lse[row]; 4 blocks per row (quarters),
// nontemporal load/store (read-once / write-once data).
// ---------------------------------------------------------------------------
__global__ __launch_bounds__(256)
void expand_sub(const __bf16* __restrict__ Lb, const float* __restrict__ lse,
                float* __restrict__ C) {
    const int row = blockIdx.x >> 2;
    const int q   = blockIdx.x & 3;
    const float s = lse[row];
    const __bf16* src = Lb + (size_t)row * VPAD;
    float* dst = C + (size_t)row * VOCAB;
    // 50257 = 8*6282 + 1; quarters of 1571 chunks (last quarter 1569 + tail)
    const int i0 = q * 1571;
    const int i1 = (q == 3) ? 6282 : i0 + 1571;
    for (int i = i0 + threadIdx.x; i < i1; i += 256) {
        bf16x8 v = __builtin_nontemporal_load((const bf16x8*)(src + i * 8));
        f32x4u a, b2;
        a[0] = (float)v[0] - s; a[1] = (float)v[1] - s;
        a[2] = (float)v[2] - s; a[3] = (float)v[3] - s;
        b2[0] = (float)v[4] - s; b2[1] = (float)v[5] - s;
        b2[2] = (float)v[6] - s; b2[3] = (float)v[7] - s;
        __builtin_nontemporal_store(a,  (f32x4u*)(dst + i * 8));
        __builtin_nontemporal_store(b2, (f32x4u*)(dst + i * 8 + 4));
    }
    if (q == 3 && threadIdx.x == 0)
        dst[50256] = (float)src[50256] - s;
}

// ---------------------------------------------------------------------------
// out[row][col] -= lse[row]; fallback when Lb doesn't fit
// ---------------------------------------------------------------------------
__global__ __launch_bounds__(256)
void sub_lse(float* __restrict__ C, const float* __restrict__ lse) {
    const int row = blockIdx.x;
    const float s = lse[row];
    float* p = C + (size_t)row * VOCAB;
    for (int i = threadIdx.x; i < 12564; i += 256) {
        f32x4u v = *(const f32x4u*)(p + 4 * i);
        v[0] -= s; v[1] -= s; v[2] -= s; v[3] -= s;
        *(f32x4u*)(p + 4 * i) = v;
    }
    if (threadIdx.x == 0) p[50256] -= s;
}

// ---------------------------------------------------------------------------
// fallback fp32-input GEMM (128x128, R1 structure) if ws too small
// ---------------------------------------------------------------------------
#define FBM 128
#define FBK 32
__device__ __forceinline__ int swz_idx(int row, int col) {
    int slot = (col >> 3) ^ ((row >> 1) & 3);
    return row * FBK + slot * 8 + (col & 7);
}

__global__ __launch_bounds__(256, 2)
void gemm_logits(const float* __restrict__ H, const float* __restrict__ W,
                 float* __restrict__ C) {
    __shared__ __bf16 ldsA[FBM * FBK];
    __shared__ __bf16 ldsB[FBM * FBK];

    const int tid  = threadIdx.x;
    const int lane = tid & 63;
    const int wave = tid >> 6;
    const int wm = (wave >> 1) * 64;
    const int wn = (wave & 1) * 64;
    const int mt = blockIdx.x;
    const int nt = blockIdx.y;
    const int srow = tid >> 1;
    const int scol = (tid & 1) * 16;
    const int brow_g = nt * FBM + srow;
    const bool bvalid = brow_g < VOCAB;
    const float* aptr = H + (size_t)(mt * FBM + srow) * EMB + scol;
    const float* bptr = W + (size_t)(bvalid ? brow_g : 0) * EMB + scol;

    f32x4 areg[4], breg[4];
    #pragma unroll
    for (int q = 0; q < 4; ++q) {
        areg[q] = *(const f32x4*)(aptr + q * 4);
        breg[q] = *(const f32x4*)(bptr + q * 4);
    }
    f32x4 acc[4][4];
    const f32x4 vzero = {0.f, 0.f, 0.f, 0.f};
    #pragma unroll
    for (int i = 0; i < 4; ++i)
        #pragma unroll
        for (int j = 0; j < 4; ++j) acc[i][j] = vzero;

    const int frow = lane & 15;
    const int kcol = (lane >> 4) * 8;

    for (int kt = 0; kt < EMB / FBK; ++kt) {
        __syncthreads();
        #pragma unroll
        for (int q = 0; q < 4; ++q) {
            const int col = scol + q * 4;
            bf16x4 av, bv;
            #pragma unroll
            for (int e = 0; e < 4; ++e) {
                av[e] = (__bf16)areg[q][e];
                bv[e] = bvalid ? (__bf16)breg[q][e] : (__bf16)0.0f;
            }
            *(bf16x4*)(&ldsA[swz_idx(srow, col)]) = av;
            *(bf16x4*)(&ldsB[swz_idx(srow, col)]) = bv;
        }
        __syncthreads();
        if (kt + 1 < EMB / FBK) {
            const int ko = (kt + 1) * FBK;
            #pragma unroll
            for (int q = 0; q < 4; ++q) {
                areg[q] = *(const f32x4*)(aptr + ko + q * 4);
                breg[q] = *(const f32x4*)(bptr + ko + q * 4);
            }
        }
        bf16x8 af[4], bfr[4];
        #pragma unroll
        for (int i = 0; i < 4; ++i) {
            af[i]  = *(const bf16x8*)(&ldsA[swz_idx(wm + i * 16 + frow, kcol)]);
            bfr[i] = *(const bf16x8*)(&ldsB[swz_idx(wn + i * 16 + frow, kcol)]);
        }
        #pragma unroll
        for (int i = 0; i < 4; ++i)
            #pragma unroll
            for (int j = 0; j < 4; ++j)
                acc[i][j] = __builtin_amdgcn_mfma_f32_16x16x32_bf16(
                    af[i], bfr[j], acc[i][j], 0, 0, 0);
    }

    const int crow = mt * FBM + wm + (lane >> 4) * 4;
    const int ccol = nt * FBM + wn + (lane & 15);
    #pragma unroll
    for (int i = 0; i < 4; ++i) {
        #pragma unroll
        for (int j = 0; j < 4; ++j) {
            const int col = ccol + j * 16;
            if (col < VOCAB) {
                #pragma unroll
                for (int r = 0; r < 4; ++r)
                    C[(size_t)(crow + i * 16 + r) * VOCAB + col] = acc[i][j][r];
            }
        }
    }
}

// ---------------------------------------------------------------------------
// fallback full row LSE
// ---------------------------------------------------------------------------
__global__ __launch_bounds__(256)
void row_lse(const float* __restrict__ C, float* __restrict__ lse) {
    const int row = blockIdx.x;
    const float* p = C + (size_t)row * VOCAB;

    float m = -INFINITY, l = 0.0f;
    for (int i = threadIdx.x; i < 12564; i += 256) {
        f32x4u v = *(const f32x4u*)(p + 4 * i);
        #pragma unroll
        for (int e = 0; e < 4; ++e) {
            const float x  = v[e];
            const float mn = fmaxf(m, x);
            l = l * __expf(m - mn) + __expf(x - mn);
            m = mn;
        }
    }
    if (threadIdx.x == 0) {
        const float x  = p[50256];
        const float mn = fmaxf(m, x);
        l = l * __expf(m - mn) + __expf(x - mn);
        m = mn;
    }
    #pragma unroll
    for (int off = 1; off < 64; off <<= 1) {
        const float mo = __shfl_xor(m, off);
        const float lo = __shfl_xor(l, off);
        const float mn = fmaxf(m, mo);
        l = l * __expf(m - mn) + lo * __expf(mo - mn);
        m = mn;
    }
    __shared__ float sm[4], sl[4];
    if ((threadIdx.x & 63) == 0) { sm[threadIdx.x >> 6] = m; sl[threadIdx.x >> 6] = l; }
    __syncthreads();
    if (threadIdx.x == 0) {
        m = sm[0]; l = sl[0];
        #pragma unroll
        for (int w = 1; w < 4; ++w) {
            const float mn = fmaxf(m, sm[w]);
            l = l * __expf(m - mn) + sl[w] * __expf(sm[w] - mn);
            m = mn;
        }
        lse[row] = m + __logf(l);
    }
}

// ---------------------------------------------------------------------------
extern "C" void kernel_launch(void* const* d_in, const int* in_sizes, int n_in,
                              void* d_out, int out_size, void* d_ws, size_t ws_size,
                              hipStream_t stream) {
    const float* H = (const float*)d_in[0];   // [4096][1024]
    const float* W = (const float*)d_in[1];   // [50257][1024]
    float* C   = (float*)d_out;               // [4096][50257]
    float* lse = (float*)d_ws;                // 4096 floats @ offset 0

    const long nH  = (long)NROWS * EMB;       // 4,194,304
    const long nW  = (long)VOCAB * EMB;       // 51,463,168
    const long nWp = (long)VPAD * EMB;        // 51,642,368

    // layout: lse | pbuf | Hb | Wb | Lb
    const size_t pb_off   = 16384;
    const size_t pb_bytes = (size_t)NT * NROWS * sizeof(float);      // 3.23 MB
    const size_t hb_off   = (pb_off + pb_bytes + 255) & ~(size_t)255;
    const size_t wb_off   = hb_off + (size_t)nH * 2;
    const size_t lb_off   = wb_off + (size_t)nWp * 2;                // ~115 MiB
    const size_t lb_bytes = (size_t)NROWS * VPAD * 2;                // 413 MB
    const size_t need_lb   = lb_off + lb_bytes;                      // ~528 MiB
    const size_t need_full = lb_off;                                 // ~115 MiB

    if (ws_size >= need_full) {
        __bf16* Hb = (__bf16*)((char*)d_ws + hb_off);
        __bf16* Wb = (__bf16*)((char*)d_ws + wb_off);
        float*  pb = (float*)((char*)d_ws + pb_off);
        cvt_bf16<<<(int)(nH / 8 / 256), 256, 0, stream>>>(H, Hb, nH, nH);
        cvt_bf16<<<(int)((nWp / 8 + 255) / 256), 256, 0, stream>>>(W, Wb, nW, nWp);
        if (ws_size >= need_lb) {
            __bf16* Lb = (__bf16*)((char*)d_ws + lb_off);
            gemm_fused<true><<<dim3(NWG), 512, 0, stream>>>(Hb, Wb, C, Lb, pb);
            lse_reduce<<<dim3(NROWS / 64), 256, 0, stream>>>(pb, lse);
            expand_sub<<<dim3(NROWS * 4), 256, 0, stream>>>(Lb, lse, C);
        } else {
            gemm_fused<false><<<dim3(NWG), 512, 0, stream>>>(Hb, Wb, C, (__bf16*)nullptr, pb);
            lse_reduce<<<dim3(NROWS / 64), 256, 0, stream>>>(pb, lse);
            sub_lse<<<dim3(NROWS), 256, 0, stream>>>(C, lse);
        }
    } else {
        dim3 ggrid(NROWS / FBM, (VOCAB + FBM - 1) / FBM);
        gemm_logits<<<ggrid, 256, 0, stream>>>(H, W, C);
        row_lse<<<dim3(NROWS), 256, 0, stream>>>(C, lse);
        sub_lse<<<dim3(NROWS), 256, 0, stream>>>(C, lse);
    }
}